// Round 2
// baseline (131.051 us; speedup 1.0000x reference)
//
#include <hip/hip_runtime.h>
#include <hip/hip_bf16.h>

// MoE gate (DeepSeek-V2 style): logits = X @ W^T, softmax, group-limited
// top-3-of-8 groups, top-6 experts, normalized weights (sorted desc).
//
// X: [T=32768, H=2048] fp32   W: [64, 2048] fp32   out: [T, 6] fp32
//
// Precision plan: fp32 = hi+mid+lo bf16 (EXACT 3-way truncation split).
// logits via 6 MFMA passes (hh, hm, mh, hl, lh, mm) -> ~1e-7 logit error,
// below numpy fp32's own rounding, so top-k selections match the reference.
// W splits precomputed into d_ws (L2-resident); X split in-register.
//
// Tiling: 32 tokens/wave (2 M-frags x 4 N-frags), single-wave blocks,
// 1024 blocks = 1 wave/SIMD, 2-step-unrolled K loop, A 2-deep / B 1-deep
// register prefetch, no barriers in the K loop.

#define HD 2048
#define NE 64

typedef __attribute__((ext_vector_type(4))) float f4;
typedef __attribute__((ext_vector_type(8))) short s8;
typedef __attribute__((ext_vector_type(4))) float accv;

struct B3 { s8 h, m, l; };

// Exact 3-way split of 8 fp32 into hi/mid/lo bf16 (truncation; residuals exact).
__device__ __forceinline__ void split8(const f4 v0, const f4 v1, s8& h, s8& m, s8& l) {
  float a[8] = {v0.x, v0.y, v0.z, v0.w, v1.x, v1.y, v1.z, v1.w};
  #pragma unroll
  for (int i = 0; i < 8; ++i) {
    unsigned u = __builtin_bit_cast(unsigned, a[i]);
    h[i] = (short)(u >> 16);
    float r1 = a[i] - __builtin_bit_cast(float, u & 0xffff0000u);
    unsigned u1 = __builtin_bit_cast(unsigned, r1);
    m[i] = (short)(u1 >> 16);
    float r2 = r1 - __builtin_bit_cast(float, u1 & 0xffff0000u);
    l[i] = (short)(__builtin_bit_cast(unsigned, r2) >> 16);
  }
}

// ---- kernel 1: split gate weights fp32 -> {hi,mid,lo} bf16 in d_ws --------
__global__ __launch_bounds__(256) void cvtW3(const float* __restrict__ Wf,
                                             unsigned short* __restrict__ Wh,
                                             unsigned short* __restrict__ Wm,
                                             unsigned short* __restrict__ Wl) {
  int i = (blockIdx.x * 256 + threadIdx.x) * 8;  // 64 blocks cover 131072
  f4 v0 = *(const f4*)(Wf + i);
  f4 v1 = *(const f4*)(Wf + i + 4);
  s8 h, m, l;
  split8(v0, v1, h, m, l);
  *(s8*)(Wh + i) = h;
  *(s8*)(Wm + i) = m;
  *(s8*)(Wl + i) = l;
}

template <bool PRE>
__device__ __forceinline__ B3 loadB(const float* __restrict__ Wf,
                                    const unsigned short* __restrict__ Wh,
                                    const unsigned short* __restrict__ Wm,
                                    const unsigned short* __restrict__ Wl,
                                    size_t base, int off) {
  B3 r;
  if constexpr (PRE) {
    r.h = *(const s8*)(Wh + base + off);
    r.m = *(const s8*)(Wm + base + off);
    r.l = *(const s8*)(Wl + base + off);
  } else {
    f4 v0 = *(const f4*)(Wf + base + off);
    f4 v1 = *(const f4*)(Wf + base + off + 4);
    split8(v0, v1, r.h, r.m, r.l);
  }
  return r;
}

__device__ __forceinline__ accv mfma6(s8 ah, s8 am, s8 al, const B3& b, accv t) {
  t = __builtin_amdgcn_mfma_f32_16x16x32_bf16(ah, b.h, t, 0, 0, 0);
  t = __builtin_amdgcn_mfma_f32_16x16x32_bf16(ah, b.m, t, 0, 0, 0);
  t = __builtin_amdgcn_mfma_f32_16x16x32_bf16(am, b.h, t, 0, 0, 0);
  t = __builtin_amdgcn_mfma_f32_16x16x32_bf16(ah, b.l, t, 0, 0, 0);
  t = __builtin_amdgcn_mfma_f32_16x16x32_bf16(al, b.h, t, 0, 0, 0);
  t = __builtin_amdgcn_mfma_f32_16x16x32_bf16(am, b.m, t, 0, 0, 0);
  return t;
}

// ---- kernel 2: fused gate --------------------------------------------------
template <bool PRE>
__global__ __launch_bounds__(64, 1) void gate6(
    const float* __restrict__ X, const float* __restrict__ Wf,
    const unsigned short* __restrict__ Wh, const unsigned short* __restrict__ Wm,
    const unsigned short* __restrict__ Wl, float* __restrict__ out) {
  __shared__ float lds[32 * 68];  // 32 tokens x 64 logits, stride 68

  const int lane = threadIdx.x;  // 0..63
  const int c = lane & 15;       // token row (A) / expert col (B)
  const int kg = lane >> 4;      // 0..3, k-offset group (8 consecutive k)
  const int tok0 = blockIdx.x * 32;

  const float* pA0 = X + (size_t)(tok0 + c) * HD + kg * 8;
  const float* pA1 = pA0 + (size_t)16 * HD;
  size_t bbase[4];
  #pragma unroll
  for (int f = 0; f < 4; ++f) bbase[f] = (size_t)(f * 16 + c) * HD + kg * 8;

  accv acc[2][4];
  #pragma unroll
  for (int mf = 0; mf < 2; ++mf)
    #pragma unroll
    for (int f = 0; f < 4; ++f) acc[mf][f] = (accv){0.f, 0.f, 0.f, 0.f};

  // raw A double-buffer: [buf][mfrag][half]
  f4 ar[2][2][2];
  B3 b[2][4];

  // prologue: A(0)->buf0, A(1)->buf1, B(0)->b[0]
  ar[0][0][0] = *(const f4*)(pA0 + 0);
  ar[0][0][1] = *(const f4*)(pA0 + 4);
  ar[0][1][0] = *(const f4*)(pA1 + 0);
  ar[0][1][1] = *(const f4*)(pA1 + 4);
  ar[1][0][0] = *(const f4*)(pA0 + 32);
  ar[1][0][1] = *(const f4*)(pA0 + 36);
  ar[1][1][0] = *(const f4*)(pA1 + 32);
  ar[1][1][1] = *(const f4*)(pA1 + 36);
  #pragma unroll
  for (int f = 0; f < 4; ++f) b[0][f] = loadB<PRE>(Wf, Wh, Wm, Wl, bbase[f], 0);

  for (int it = 0; it < 32; ++it) {
    const int s = 2 * it;
    // ===== even step s: consume ar[0], b[0] =====
    {
      s8 ah[2], am[2], al[2];
      #pragma unroll
      for (int mf = 0; mf < 2; ++mf) split8(ar[0][mf][0], ar[0][mf][1], ah[mf], am[mf], al[mf]);
      // prefetch A(s+2)->ar[0], B(s+1)->b[1]
      const int oA = (s + 2 < 64 ? s + 2 : 63) * 32;
      const int oB = (s + 1 < 64 ? s + 1 : 63) * 32;
      ar[0][0][0] = *(const f4*)(pA0 + oA);
      ar[0][0][1] = *(const f4*)(pA0 + oA + 4);
      ar[0][1][0] = *(const f4*)(pA1 + oA);
      ar[0][1][1] = *(const f4*)(pA1 + oA + 4);
      #pragma unroll
      for (int f = 0; f < 4; ++f) b[1][f] = loadB<PRE>(Wf, Wh, Wm, Wl, bbase[f], oB);
      #pragma unroll
      for (int mf = 0; mf < 2; ++mf)
        #pragma unroll
        for (int f = 0; f < 4; ++f)
          acc[mf][f] = mfma6(ah[mf], am[mf], al[mf], b[0][f], acc[mf][f]);
    }
    // ===== odd step s+1: consume ar[1], b[1] =====
    {
      s8 ah[2], am[2], al[2];
      #pragma unroll
      for (int mf = 0; mf < 2; ++mf) split8(ar[1][mf][0], ar[1][mf][1], ah[mf], am[mf], al[mf]);
      // prefetch A(s+3)->ar[1], B(s+2)->b[0]
      const int oA = (s + 3 < 64 ? s + 3 : 63) * 32;
      const int oB = (s + 2 < 64 ? s + 2 : 63) * 32;
      ar[1][0][0] = *(const f4*)(pA0 + oA);
      ar[1][0][1] = *(const f4*)(pA0 + oA + 4);
      ar[1][1][0] = *(const f4*)(pA1 + oA);
      ar[1][1][1] = *(const f4*)(pA1 + oA + 4);
      #pragma unroll
      for (int f = 0; f < 4; ++f) b[0][f] = loadB<PRE>(Wf, Wh, Wm, Wl, bbase[f], oB);
      #pragma unroll
      for (int mf = 0; mf < 2; ++mf)
        #pragma unroll
        for (int f = 0; f < 4; ++f)
          acc[mf][f] = mfma6(ah[mf], am[mf], al[mf], b[1][f], acc[mf][f]);
    }
  }

  // --- scatter logits to LDS: C/D layout col=lane&15, row=(lane>>4)*4+r ---
  #pragma unroll
  for (int mf = 0; mf < 2; ++mf)
    #pragma unroll
    for (int f = 0; f < 4; ++f)
      #pragma unroll
      for (int r = 0; r < 4; ++r)
        lds[(mf * 16 + kg * 4 + r) * 68 + f * 16 + c] = acc[mf][f][r];
  __syncthreads();

  // --- per-token epilogue: one token per lane (lanes 0..31) ---
  if (lane < 32) {
    const f4* rp = (const f4*)(lds + lane * 68);
    float v[64];
    #pragma unroll
    for (int i = 0; i < 16; ++i) {
      f4 q = rp[i];
      v[4 * i + 0] = q.x; v[4 * i + 1] = q.y;
      v[4 * i + 2] = q.z; v[4 * i + 3] = q.w;
    }
    // group maxes on logits (softmax monotonic -> same selection)
    float gm[8];
    #pragma unroll
    for (int g = 0; g < 8; ++g) {
      float mx = v[g * 8];
      #pragma unroll
      for (int j = 1; j < 8; ++j) mx = fmaxf(mx, v[g * 8 + j]);
      gm[g] = mx;
    }
    // top-3 groups, ties -> lowest index (matches lax.top_k)
    unsigned selmask = 0u;
    #pragma unroll
    for (int itg = 0; itg < 3; ++itg) {
      float best = gm[0];
      #pragma unroll
      for (int g = 1; g < 8; ++g) best = fmaxf(best, gm[g]);
      int bi = 7;
      #pragma unroll
      for (int g = 6; g >= 0; --g)
        if (gm[g] == best) bi = g;
      selmask |= (1u << bi);
      #pragma unroll
      for (int g = 0; g < 8; ++g) gm[g] = (g == bi) ? -3.0e38f : gm[g];
    }
    // top-6 of selected-group logits, branchless insertion network (sorted desc)
    float t0 = -3.0e38f, t1 = -3.0e38f, t2 = -3.0e38f;
    float t3 = -3.0e38f, t4 = -3.0e38f, t5 = -3.0e38f;
    #pragma unroll
    for (int g = 0; g < 8; ++g) {
      const bool sel = (selmask >> g) & 1u;
      #pragma unroll
      for (int j = 0; j < 8; ++j) {
        float x = sel ? v[g * 8 + j] : -3.0e38f;
        float mm;
        mm = fmaxf(t0, x); x = fminf(t0, x); t0 = mm;
        mm = fmaxf(t1, x); x = fminf(t1, x); t1 = mm;
        mm = fmaxf(t2, x); x = fminf(t2, x); t2 = mm;
        mm = fmaxf(t3, x); x = fminf(t3, x); t3 = mm;
        mm = fmaxf(t4, x); x = fminf(t4, x); t4 = mm;
        t5 = fmaxf(t5, x);
      }
    }
    // normalized softmax over the selected 6 (global denom cancels exactly)
    float e0 = 1.0f;
    float e1 = __expf(t1 - t0);
    float e2 = __expf(t2 - t0);
    float e3 = __expf(t3 - t0);
    float e4 = __expf(t4 - t0);
    float e5 = __expf(t5 - t0);
    float sum = e0 + e1 + e2 + e3 + e4 + e5;
    float inv = 1.0f / sum;
    float* op = out + (size_t)(tok0 + lane) * 6;
    op[0] = e0 * inv; op[1] = e1 * inv; op[2] = e2 * inv;
    op[3] = e3 * inv; op[4] = e4 * inv; op[5] = e5 * inv;
  }
}

extern "C" void kernel_launch(void* const* d_in, const int* in_sizes, int n_in,
                              void* d_out, int out_size, void* d_ws, size_t ws_size,
                              hipStream_t stream) {
  const float* X = (const float*)d_in[0];
  const float* Wf = (const float*)d_in[1];
  float* out = (float*)d_out;
  const int T = in_sizes[0] / HD;  // 32768
  const int nblk = T / 32;         // 1024 single-wave blocks

  const size_t need = (size_t)NE * HD * sizeof(unsigned short);  // 256 KB per split
  if (ws_size >= 3 * need) {
    unsigned short* Whi = (unsigned short*)d_ws;
    unsigned short* Wmi = Whi + (size_t)NE * HD;
    unsigned short* Wlo = Wmi + (size_t)NE * HD;
    cvtW3<<<dim3(64), dim3(256), 0, stream>>>(Wf, Whi, Wmi, Wlo);
    gate6<true><<<dim3(nblk), dim3(64), 0, stream>>>(X, Wf, Whi, Wmi, Wlo, out);
  } else {
    gate6<false><<<dim3(nblk), dim3(64), 0, stream>>>(X, Wf, nullptr, nullptr, nullptr, out);
  }
}